// Round 3
// baseline (343.355 us; speedup 1.0000x reference)
//
#include <hip/hip_runtime.h>
#include <stdint.h>

#define DEVINL __device__ __forceinline__

typedef short bf16x8 __attribute__((ext_vector_type(8)));
typedef float f32x4  __attribute__((ext_vector_type(4)));

// ---------- bf16 helpers (RNE) ----------
DEVINL uint16_t f2bf(float f) {
    uint32_t u = __builtin_bit_cast(uint32_t, f);
    uint32_t r = u + 0x7fffu + ((u >> 16) & 1u);
    return (uint16_t)(r >> 16);
}

DEVINL f32x4 mfma16x16x32(bf16x8 a, bf16x8 b, f32x4 c) {
    return __builtin_amdgcn_mfma_f32_16x16x32_bf16(a, b, c, 0, 0, 0);
}

// async global->LDS, 16 B per lane; LDS dest = wave-uniform base + lane*16
DEVINL void async_load16(const void* g, void* l) {
    __builtin_amdgcn_global_load_lds(
        (const __attribute__((address_space(1))) void*)g,
        (__attribute__((address_space(3))) void*)l, 16, 0, 0);
}

// ---------- ws layout (bytes) ----------
// We1T bf16 [256][800] @ 0       size 409600  (cols 784..799 zero)
// We2T bf16 [32][256]  @ 409600  size 16384
// W1T  bf16 [128][32]  @ 425984  size 8192
// W2T  bf16 [16][128]  @ 434176  size 4096    (cols 10..15 zero)
#define WS_WE1T 0
#define WS_WE2T 409600
#define WS_W1T  425984
#define WS_W2T  434176

// ================= prep: transpose + f32->bf16 weights =================
__global__ __launch_bounds__(256) void prep_weights(
    const float* __restrict__ We1, const float* __restrict__ We2,
    const float* __restrict__ W1,  const float* __restrict__ W2,
    uint16_t* __restrict__ We1T, uint16_t* __restrict__ We2T,
    uint16_t* __restrict__ W1T,  uint16_t* __restrict__ W2T) {
    int tid = blockIdx.x * 256 + threadIdx.x;
    if (tid < 256 * 800) {                   // We1T[n][k] = We1[k][n], k-pad to 800
        int n = tid / 800, k = tid % 800;
        We1T[tid] = (k < 784) ? f2bf(We1[k * 256 + n]) : (uint16_t)0;
        return;
    }
    int t2 = tid - 256 * 800;
    if (t2 < 32 * 256) {                     // We2T[n][k] = We2[k][n]
        int n = t2 / 256, k = t2 % 256;
        We2T[t2] = f2bf(We2[k * 32 + n]);
        return;
    }
    int t3 = t2 - 32 * 256;
    if (t3 < 128 * 32) {                     // W1T[n][k] = W1[k][n]
        int n = t3 / 32, k = t3 % 32;
        W1T[t3] = f2bf(W1[k * 128 + n]);
        return;
    }
    int t4 = t3 - 128 * 32;
    if (t4 < 16 * 128) {                     // W2T[n][k] = W2[k][n], pad n>=10 with 0
        int n = t4 / 128, k = t4 % 128;
        W2T[t4] = (n < 10) ? f2bf(W2[k * 10 + n]) : (uint16_t)0;
        return;
    }
}

// ================= quantum circuit (fixed angles, fully unrolled) =================
DEVINL void apply_rx(float* sr, float* si, int bit, float c, float s) {
    #pragma unroll
    for (int i = 0; i < 16; i++) {
        if (!(i & bit)) {
            int j = i | bit;
            float r0 = sr[i], i0 = si[i], r1 = sr[j], i1 = si[j];
            sr[i] = c * r0 + s * i1;  si[i] = c * i0 - s * r1;
            sr[j] = c * r1 + s * i0;  si[j] = c * i1 - s * r0;
        }
    }
}
DEVINL void apply_ry(float* sr, float* si, int bit, float c, float s) {
    #pragma unroll
    for (int i = 0; i < 16; i++) {
        if (!(i & bit)) {
            int j = i | bit;
            float r0 = sr[i], i0 = si[i], r1 = sr[j], i1 = si[j];
            sr[i] = c * r0 - s * r1;  si[i] = c * i0 - s * i1;
            sr[j] = s * r0 + c * r1;  si[j] = s * i0 + c * i1;
        }
    }
}
DEVINL void apply_cnot(float* sr, float* si, int cb, int tb) {
    #pragma unroll
    for (int i = 0; i < 16; i++) {
        if ((i & cb) && !(i & tb)) {
            int j = i | tb;
            float tr = sr[i]; sr[i] = sr[j]; sr[j] = tr;
            float ti = si[i]; si[i] = si[j]; si[j] = ti;
        }
    }
}
DEVINL void circuit(float* sr, float* si) {
    const float C1 = 0.99875026039496628f, S1 = 0.04997916927067833f;  // rx(0.1)
    const float C2 = 0.99500416527802582f, S2 = 0.09983341664682815f;  // ry(0.2)
    const float C3 = 0.98877107793604227f, S3 = 0.14943813247359922f;  // rx(0.3)
    const float C4 = 0.98006657784124163f, S4 = 0.19866933079506122f;  // ry(0.4)
    #pragma unroll
    for (int q = 0; q < 4; q++) {
        int bit = 8 >> q;
        apply_rx(sr, si, bit, C1, S1);
        apply_ry(sr, si, bit, C2, S2);
    }
    apply_cnot(sr, si, 8, 4);
    apply_cnot(sr, si, 4, 2);
    apply_cnot(sr, si, 2, 1);
    #pragma unroll
    for (int q = 0; q < 4; q++) {
        int bit = 8 >> q;
        apply_rx(sr, si, bit, C3, S3);
        apply_ry(sr, si, bit, C4, S4);
    }
}

// ================= fused: GEMM1+relu + GEMM2+tanh + norm+circuit + classifier =================
// 1024 blocks x 256 thr (4 waves); 64 rows/block; N-tile 256 = full h width.
// LDS 55296 B -> 2 blocks/CU. Main loop: unpadded stride-32 tiles (conflict-free,
// global_load_lds-compatible); tail runs entirely in-block (no h round-trip).
__global__ __launch_bounds__(256, 2) void fused_kernel(
    const float* __restrict__ x, const uint16_t* __restrict__ We1T,
    const float* __restrict__ be1,
    const uint16_t* __restrict__ We2T, const float* __restrict__ be2,
    const uint16_t* __restrict__ W1T, const float* __restrict__ b1,
    const uint16_t* __restrict__ W2T, const float* __restrict__ b2,
    float* __restrict__ out) {
    __shared__ __align__(16) char smem[55296];
    uint16_t* Htile  = (uint16_t*)smem;              // [64][272] bf16 = 34816 B; later a1 [64][136]
    uint16_t* Als    = (uint16_t*)(smem + 34816);    // [64][32]  = 4096 B
    uint16_t* Bls    = (uint16_t*)(smem + 38912);    // [256][32] = 16384 B
    float*    encls  = (float*)(smem + 34816);       // [64][33] f32 = 8448 B (aliases Als/Bls, dead then)
    uint16_t* featls = (uint16_t*)(smem + 43264);    // [64][40] bf16 = 5120 B

    const int t = threadIdx.x;
    const int rowbase = blockIdx.x * 64;
    const int w  = t >> 6;     // wave 0..3 -> n-block w*64 in GEMM1; rows w*16.. in tail
    const int l  = t & 63;
    const int lm = l & 15;
    const int lq = l >> 4;

    f32x4 acc[4][4] = {};      // GEMM1: [mi][ni] -> rows mi*16.., cols w*64+ni*16..

    // A staging: thread t loads row ar, 8 f32 at col aq*8
    const int ar = t >> 2;
    const int aq = t & 3;
    const float* xrow = x + (size_t)(rowbase + ar) * 784;

    float4 va0 = *(const float4*)(xrow + aq * 8);
    float4 va1 = *(const float4*)(xrow + aq * 8 + 4);

    for (int k0 = 0; k0 < 800; k0 += 32) {
        __syncthreads();       // prev tile fully consumed

        // ---- async B stage: 4 x 16 B chunks/thread (zeros past k=784 from padded We1T) ----
        #pragma unroll
        for (int j = 0; j < 4; j++) {
            int g = j * 256 + t;
            async_load16(We1T + (size_t)(g >> 2) * 800 + (g & 3) * 8 + k0, &Bls[8 * g]);
        }
        // ---- convert prefetched A regs -> LDS ----
        union { uint4 u4; uint16_t us[8]; } pk;
        pk.us[0] = f2bf(va0.x); pk.us[1] = f2bf(va0.y);
        pk.us[2] = f2bf(va0.z); pk.us[3] = f2bf(va0.w);
        pk.us[4] = f2bf(va1.x); pk.us[5] = f2bf(va1.y);
        pk.us[6] = f2bf(va1.z); pk.us[7] = f2bf(va1.w);
        *(uint4*)&Als[8 * t] = pk.u4;
        // ---- prefetch next A tile ----
        {
            int kn = k0 + 32;
            if (kn < 800) {
                int c = kn + aq * 8;
                if (c < 784) {
                    va0 = *(const float4*)(xrow + c);
                    va1 = *(const float4*)(xrow + c + 4);
                } else {
                    va0 = make_float4(0.f, 0.f, 0.f, 0.f);
                    va1 = make_float4(0.f, 0.f, 0.f, 0.f);
                }
            }
        }
        __syncthreads();       // staging visible

        bf16x8 afr[4], bfr[4];
        #pragma unroll
        for (int mi = 0; mi < 4; mi++)
            afr[mi] = *(const bf16x8*)&Als[(mi * 16 + lm) * 32 + lq * 8];
        #pragma unroll
        for (int ni = 0; ni < 4; ni++)
            bfr[ni] = *(const bf16x8*)&Bls[(w * 64 + ni * 16 + lm) * 32 + lq * 8];
        #pragma unroll
        for (int mi = 0; mi < 4; mi++)
            #pragma unroll
            for (int ni = 0; ni < 4; ni++)
                acc[mi][ni] = mfma16x16x32(afr[mi], bfr[ni], acc[mi][ni]);
    }

    // ---- GEMM1 epilogue: relu(+bias) -> Htile bf16 [64][272] ----
    #pragma unroll
    for (int ni = 0; ni < 4; ni++) {
        int n = w * 64 + ni * 16 + lm;
        float bias = be1[n];
        #pragma unroll
        for (int mi = 0; mi < 4; mi++) {
            #pragma unroll
            for (int i = 0; i < 4; i++) {
                int r = mi * 16 + lq * 4 + i;
                float v = acc[mi][ni][i] + bias;
                v = v > 0.f ? v : 0.f;
                Htile[r * 272 + n] = f2bf(v);
            }
        }
    }
    __syncthreads();   // Htile complete; Als/Bls dead

    // ---- GEMM2: enc_pre = h @ We2, K=256; B frags direct from global (L2-hot) ----
    f32x4 acc2[2] = {};
    #pragma unroll
    for (int k0 = 0; k0 < 256; k0 += 32) {
        bf16x8 af = *(const bf16x8*)&Htile[(w * 16 + lm) * 272 + k0 + lq * 8];
        #pragma unroll
        for (int ni = 0; ni < 2; ni++) {
            bf16x8 bf = *(const bf16x8*)&We2T[(ni * 16 + lm) * 256 + k0 + lq * 8];
            acc2[ni] = mfma16x16x32(af, bf, acc2[ni]);
        }
    }
    // ---- enc = tanh(acc + be2) -> LDS ----
    #pragma unroll
    for (int ni = 0; ni < 2; ni++) {
        int col = ni * 16 + lm;
        float bias = be2[col];
        #pragma unroll
        for (int i = 0; i < 4; i++) {
            int r = w * 16 + lq * 4 + i;
            encls[r * 33 + col] = tanhf(acc2[ni][i] + bias);
        }
    }
    __syncthreads();   // enc visible cross-wave; Htile reads all done

    // ---- per-row: normalize + quantum circuit -> feat bf16 ----
    if (t < 64) {
        float e[32];
        #pragma unroll
        for (int j = 0; j < 32; j++) e[j] = encls[t * 33 + j];
        float s = 0.f;
        #pragma unroll
        for (int j = 0; j < 32; j++) s += e[j] * e[j];
        float inv = 1.0f / sqrtf(s);
        float sr[16], si[16];
        #pragma unroll
        for (int i = 0; i < 16; i++) { sr[i] = e[i] * inv; si[i] = e[16 + i] * inv; }
        circuit(sr, si);
        #pragma unroll
        for (int i = 0; i < 16; i++) {
            featls[t * 40 + i]      = f2bf(sr[i]);
            featls[t * 40 + 16 + i] = f2bf(si[i]);
        }
    }
    __syncthreads();   // feat visible cross-wave

    // ---- classifier L1: a1 = relu(feat @ W1 + b1), K=32; a1 reuses Htile region ----
    uint16_t* a1ls = (uint16_t*)smem;   // [64][136] bf16
    f32x4 acc3[8] = {};
    {
        bf16x8 af = *(const bf16x8*)&featls[(w * 16 + lm) * 40 + lq * 8];
        #pragma unroll
        for (int ni = 0; ni < 8; ni++) {
            bf16x8 bf = *(const bf16x8*)&W1T[(ni * 16 + lm) * 32 + lq * 8];
            acc3[ni] = mfma16x16x32(af, bf, acc3[ni]);
        }
    }
    #pragma unroll
    for (int ni = 0; ni < 8; ni++) {
        int col = ni * 16 + lm;
        float bias = b1[col];
        #pragma unroll
        for (int i = 0; i < 4; i++) {
            int r = w * 16 + lq * 4 + i;   // rows w*16..+15: same wave writes & reads
            float v = acc3[ni][i] + bias;
            v = v > 0.f ? v : 0.f;
            a1ls[r * 136 + col] = f2bf(v);
        }
    }
    // no barrier: wave w wrote exactly the a1 rows it reads below (same-wave LDS order)

    // ---- classifier L2: out = a1 @ W2 + b2, K=128, N=16 (10 real) ----
    f32x4 acc4 = {};
    #pragma unroll
    for (int k0 = 0; k0 < 128; k0 += 32) {
        bf16x8 af = *(const bf16x8*)&a1ls[(w * 16 + lm) * 136 + k0 + lq * 8];
        bf16x8 bf = *(const bf16x8*)&W2T[lm * 128 + k0 + lq * 8];
        acc4 = mfma16x16x32(af, bf, acc4);
    }
    if (lm < 10) {
        float bias = b2[lm];
        #pragma unroll
        for (int i = 0; i < 4; i++) {
            int r = rowbase + w * 16 + lq * 4 + i;
            out[(size_t)r * 10 + lm] = acc4[i] + bias;
        }
    }
}

extern "C" void kernel_launch(void* const* d_in, const int* in_sizes, int n_in,
                              void* d_out, int out_size, void* d_ws, size_t ws_size,
                              hipStream_t stream) {
    const float* x   = (const float*)d_in[0];
    const float* We1 = (const float*)d_in[1];
    const float* be1 = (const float*)d_in[2];
    const float* We2 = (const float*)d_in[3];
    const float* be2 = (const float*)d_in[4];
    const float* W1  = (const float*)d_in[5];
    const float* b1  = (const float*)d_in[6];
    const float* W2  = (const float*)d_in[7];
    const float* b2  = (const float*)d_in[8];
    float* out = (float*)d_out;

    char* ws = (char*)d_ws;
    uint16_t* We1T = (uint16_t*)(ws + WS_WE1T);
    uint16_t* We2T = (uint16_t*)(ws + WS_WE2T);
    uint16_t* W1T  = (uint16_t*)(ws + WS_W1T);
    uint16_t* W2T  = (uint16_t*)(ws + WS_W2T);

    hipLaunchKernelGGL(prep_weights, dim3(856), dim3(256), 0, stream,
                       We1, We2, W1, W2, We1T, We2T, W1T, W2T);
    hipLaunchKernelGGL(fused_kernel, dim3(1024), dim3(256), 0, stream,
                       x, We1T, be1, We2T, be2, W1T, b1, W2T, b2, out);
}

// Round 4
// 323.204 us; speedup vs baseline: 1.0623x; 1.0623x over previous
//
#include <hip/hip_runtime.h>
#include <stdint.h>

#define DEVINL __device__ __forceinline__

typedef short bf16x8 __attribute__((ext_vector_type(8)));
typedef float f32x4  __attribute__((ext_vector_type(4)));

// ---------- bf16 helpers (RNE) ----------
DEVINL uint16_t f2bf(float f) {
    uint32_t u = __builtin_bit_cast(uint32_t, f);
    uint32_t r = u + 0x7fffu + ((u >> 16) & 1u);
    return (uint16_t)(r >> 16);
}

DEVINL f32x4 mfma16x16x32(bf16x8 a, bf16x8 b, f32x4 c) {
    return __builtin_amdgcn_mfma_f32_16x16x32_bf16(a, b, c, 0, 0, 0);
}

// async global->LDS, 16 B per lane; LDS dest = wave-uniform base + lane*16
DEVINL void async_load16(const void* g, void* l) {
    __builtin_amdgcn_global_load_lds(
        (const __attribute__((address_space(1))) void*)g,
        (__attribute__((address_space(3))) void*)l, 16, 0, 0);
}

// ---------- ws layout (bytes) ----------
// We1T bf16 [256][800] @ 0       size 409600  (cols 784..799 zero)
// We2T bf16 [32][256]  @ 409600  size 16384
// W1T  bf16 [128][32]  @ 425984  size 8192
// W2T  bf16 [16][128]  @ 434176  size 4096    (cols 10..15 zero)
#define WS_WE1T 0
#define WS_WE2T 409600
#define WS_W1T  425984
#define WS_W2T  434176

// ================= prep: transpose + f32->bf16 weights =================
__global__ __launch_bounds__(256) void prep_weights(
    const float* __restrict__ We1, const float* __restrict__ We2,
    const float* __restrict__ W1,  const float* __restrict__ W2,
    uint16_t* __restrict__ We1T, uint16_t* __restrict__ We2T,
    uint16_t* __restrict__ W1T,  uint16_t* __restrict__ W2T) {
    int tid = blockIdx.x * 256 + threadIdx.x;
    if (tid < 256 * 800) {                   // We1T[n][k] = We1[k][n], k-pad to 800
        int n = tid / 800, k = tid % 800;
        We1T[tid] = (k < 784) ? f2bf(We1[k * 256 + n]) : (uint16_t)0;
        return;
    }
    int t2 = tid - 256 * 800;
    if (t2 < 32 * 256) {                     // We2T[n][k] = We2[k][n]
        int n = t2 / 256, k = t2 % 256;
        We2T[t2] = f2bf(We2[k * 32 + n]);
        return;
    }
    int t3 = t2 - 32 * 256;
    if (t3 < 128 * 32) {                     // W1T[n][k] = W1[k][n]
        int n = t3 / 32, k = t3 % 32;
        W1T[t3] = f2bf(W1[k * 128 + n]);
        return;
    }
    int t4 = t3 - 128 * 32;
    if (t4 < 16 * 128) {                     // W2T[n][k] = W2[k][n], pad n>=10 with 0
        int n = t4 / 128, k = t4 % 128;
        W2T[t4] = (n < 10) ? f2bf(W2[k * 10 + n]) : (uint16_t)0;
        return;
    }
}

// ================= quantum circuit (fixed angles, fully unrolled) =================
DEVINL void apply_rx(float* sr, float* si, int bit, float c, float s) {
    #pragma unroll
    for (int i = 0; i < 16; i++) {
        if (!(i & bit)) {
            int j = i | bit;
            float r0 = sr[i], i0 = si[i], r1 = sr[j], i1 = si[j];
            sr[i] = c * r0 + s * i1;  si[i] = c * i0 - s * r1;
            sr[j] = c * r1 + s * i0;  si[j] = c * i1 - s * r0;
        }
    }
}
DEVINL void apply_ry(float* sr, float* si, int bit, float c, float s) {
    #pragma unroll
    for (int i = 0; i < 16; i++) {
        if (!(i & bit)) {
            int j = i | bit;
            float r0 = sr[i], i0 = si[i], r1 = sr[j], i1 = si[j];
            sr[i] = c * r0 - s * r1;  si[i] = c * i0 - s * i1;
            sr[j] = s * r0 + c * r1;  si[j] = s * i0 + c * i1;
        }
    }
}
DEVINL void apply_cnot(float* sr, float* si, int cb, int tb) {
    #pragma unroll
    for (int i = 0; i < 16; i++) {
        if ((i & cb) && !(i & tb)) {
            int j = i | tb;
            float tr = sr[i]; sr[i] = sr[j]; sr[j] = tr;
            float ti = si[i]; si[i] = si[j]; si[j] = ti;
        }
    }
}
DEVINL void circuit(float* sr, float* si) {
    const float C1 = 0.99875026039496628f, S1 = 0.04997916927067833f;  // rx(0.1)
    const float C2 = 0.99500416527802582f, S2 = 0.09983341664682815f;  // ry(0.2)
    const float C3 = 0.98877107793604227f, S3 = 0.14943813247359922f;  // rx(0.3)
    const float C4 = 0.98006657784124163f, S4 = 0.19866933079506122f;  // ry(0.4)
    #pragma unroll
    for (int q = 0; q < 4; q++) {
        int bit = 8 >> q;
        apply_rx(sr, si, bit, C1, S1);
        apply_ry(sr, si, bit, C2, S2);
    }
    apply_cnot(sr, si, 8, 4);
    apply_cnot(sr, si, 4, 2);
    apply_cnot(sr, si, 2, 1);
    #pragma unroll
    for (int q = 0; q < 4; q++) {
        int bit = 8 >> q;
        apply_rx(sr, si, bit, C3, S3);
        apply_ry(sr, si, bit, C4, S4);
    }
}

// ================= fused: GEMM1+relu + GEMM2+tanh + norm+circuit + classifier =================
// 1024 blocks x 256 thr (4 waves); 64 rows/block; N-tile 256 = full h width.
// LDS: ONE 34816-B arena, time-aliased (staging -> Htile -> enc/feat/a1) with
// barriers at each lifetime boundary -> 4 blocks/CU (16 waves/CU), and the
// 1024-block grid fills all 1024 resident slots in a single round.
__global__ __launch_bounds__(256, 4) void fused_kernel(
    const float* __restrict__ x, const uint16_t* __restrict__ We1T,
    const float* __restrict__ be1,
    const uint16_t* __restrict__ We2T, const float* __restrict__ be2,
    const uint16_t* __restrict__ W1T, const float* __restrict__ b1,
    const uint16_t* __restrict__ W2T, const float* __restrict__ b2,
    float* __restrict__ out) {
    __shared__ __align__(16) char smem[34816];
    // phase 1 (K-loop): staging
    uint16_t* Als   = (uint16_t*)smem;             // [64][32]  = 4096 B
    uint16_t* Bls   = (uint16_t*)(smem + 4096);    // [256][32] = 16384 B
    // phase 2 (epilogue..GEMM2): Htile [64][272] bf16 = 34816 B (whole arena)
    uint16_t* Htile = (uint16_t*)smem;
    // phase 3 (tail): enc/feat/a1
    float*    encls  = (float*)smem;               // [64][33] f32 = 8448 B
    uint16_t* featls = (uint16_t*)(smem + 8448);   // [64][40] bf16 = 5120 B
    uint16_t* a1ls   = (uint16_t*)(smem + 13568);  // [64][136] bf16 = 17408 B (ends 30976)

    const int t = threadIdx.x;
    const int rowbase = blockIdx.x * 64;
    const int w  = t >> 6;     // wave 0..3 -> n-block w*64 in GEMM1; rows w*16.. in tail
    const int l  = t & 63;
    const int lm = l & 15;
    const int lq = l >> 4;

    f32x4 acc[4][4] = {};      // GEMM1: [mi][ni] -> rows mi*16.., cols w*64+ni*16..

    // A staging: thread t loads row ar, 8 f32 at col aq*8
    const int ar = t >> 2;
    const int aq = t & 3;
    const float* xrow = x + (size_t)(rowbase + ar) * 784;

    float4 va0 = *(const float4*)(xrow + aq * 8);
    float4 va1 = *(const float4*)(xrow + aq * 8 + 4);

    for (int k0 = 0; k0 < 800; k0 += 32) {
        __syncthreads();       // prev tile fully consumed

        // ---- async B stage: 4 x 16 B chunks/thread (zeros past k=784 from padded We1T) ----
        #pragma unroll
        for (int j = 0; j < 4; j++) {
            int g = j * 256 + t;
            async_load16(We1T + (size_t)(g >> 2) * 800 + (g & 3) * 8 + k0, &Bls[8 * g]);
        }
        // ---- convert prefetched A regs -> LDS ----
        union { uint4 u4; uint16_t us[8]; } pk;
        pk.us[0] = f2bf(va0.x); pk.us[1] = f2bf(va0.y);
        pk.us[2] = f2bf(va0.z); pk.us[3] = f2bf(va0.w);
        pk.us[4] = f2bf(va1.x); pk.us[5] = f2bf(va1.y);
        pk.us[6] = f2bf(va1.z); pk.us[7] = f2bf(va1.w);
        *(uint4*)&Als[8 * t] = pk.u4;
        // ---- prefetch next A tile ----
        {
            int kn = k0 + 32;
            if (kn < 800) {
                int c = kn + aq * 8;
                if (c < 784) {
                    va0 = *(const float4*)(xrow + c);
                    va1 = *(const float4*)(xrow + c + 4);
                } else {
                    va0 = make_float4(0.f, 0.f, 0.f, 0.f);
                    va1 = make_float4(0.f, 0.f, 0.f, 0.f);
                }
            }
        }
        __syncthreads();       // staging visible

        bf16x8 afr[4], bfr[4];
        #pragma unroll
        for (int mi = 0; mi < 4; mi++)
            afr[mi] = *(const bf16x8*)&Als[(mi * 16 + lm) * 32 + lq * 8];
        #pragma unroll
        for (int ni = 0; ni < 4; ni++)
            bfr[ni] = *(const bf16x8*)&Bls[(w * 64 + ni * 16 + lm) * 32 + lq * 8];
        #pragma unroll
        for (int mi = 0; mi < 4; mi++)
            #pragma unroll
            for (int ni = 0; ni < 4; ni++)
                acc[mi][ni] = mfma16x16x32(afr[mi], bfr[ni], acc[mi][ni]);
    }

    __syncthreads();   // all waves' staging reads done; arena becomes Htile

    // ---- GEMM1 epilogue: relu(+bias) -> Htile bf16 [64][272] ----
    #pragma unroll
    for (int ni = 0; ni < 4; ni++) {
        int n = w * 64 + ni * 16 + lm;
        float bias = be1[n];
        #pragma unroll
        for (int mi = 0; mi < 4; mi++) {
            #pragma unroll
            for (int i = 0; i < 4; i++) {
                int r = mi * 16 + lq * 4 + i;
                float v = acc[mi][ni][i] + bias;
                v = v > 0.f ? v : 0.f;
                Htile[r * 272 + n] = f2bf(v);
            }
        }
    }
    __syncthreads();   // Htile complete

    // ---- GEMM2: enc_pre = h @ We2, K=256; B frags direct from global (L2-hot) ----
    f32x4 acc2[2] = {};
    #pragma unroll
    for (int k0 = 0; k0 < 256; k0 += 32) {
        bf16x8 af = *(const bf16x8*)&Htile[(w * 16 + lm) * 272 + k0 + lq * 8];
        #pragma unroll
        for (int ni = 0; ni < 2; ni++) {
            bf16x8 bf = *(const bf16x8*)&We2T[(ni * 16 + lm) * 256 + k0 + lq * 8];
            acc2[ni] = mfma16x16x32(af, bf, acc2[ni]);
        }
    }
    __syncthreads();   // all waves' Htile reads done; arena becomes enc/feat/a1

    // ---- enc = tanh(acc + be2) -> LDS ----
    #pragma unroll
    for (int ni = 0; ni < 2; ni++) {
        int col = ni * 16 + lm;
        float bias = be2[col];
        #pragma unroll
        for (int i = 0; i < 4; i++) {
            int r = w * 16 + lq * 4 + i;
            encls[r * 33 + col] = tanhf(acc2[ni][i] + bias);
        }
    }
    __syncthreads();   // enc visible cross-wave

    // ---- per-row: normalize + quantum circuit -> feat bf16 ----
    if (t < 64) {
        float e[32];
        #pragma unroll
        for (int j = 0; j < 32; j++) e[j] = encls[t * 33 + j];
        float s = 0.f;
        #pragma unroll
        for (int j = 0; j < 32; j++) s += e[j] * e[j];
        float inv = 1.0f / sqrtf(s);
        float sr[16], si[16];
        #pragma unroll
        for (int i = 0; i < 16; i++) { sr[i] = e[i] * inv; si[i] = e[16 + i] * inv; }
        circuit(sr, si);
        #pragma unroll
        for (int i = 0; i < 16; i++) {
            featls[t * 40 + i]      = f2bf(sr[i]);
            featls[t * 40 + 16 + i] = f2bf(si[i]);
        }
    }
    __syncthreads();   // feat visible cross-wave

    // ---- classifier L1: a1 = relu(feat @ W1 + b1), K=32 ----
    f32x4 acc3[8] = {};
    {
        bf16x8 af = *(const bf16x8*)&featls[(w * 16 + lm) * 40 + lq * 8];
        #pragma unroll
        for (int ni = 0; ni < 8; ni++) {
            bf16x8 bf = *(const bf16x8*)&W1T[(ni * 16 + lm) * 32 + lq * 8];
            acc3[ni] = mfma16x16x32(af, bf, acc3[ni]);
        }
    }
    #pragma unroll
    for (int ni = 0; ni < 8; ni++) {
        int col = ni * 16 + lm;
        float bias = b1[col];
        #pragma unroll
        for (int i = 0; i < 4; i++) {
            int r = w * 16 + lq * 4 + i;   // rows w*16..+15: same wave writes & reads
            float v = acc3[ni][i] + bias;
            v = v > 0.f ? v : 0.f;
            a1ls[r * 136 + col] = f2bf(v);
        }
    }
    // no barrier: wave w wrote exactly the a1 rows it reads below (same-wave LDS order)

    // ---- classifier L2: out = a1 @ W2 + b2, K=128, N=16 (10 real) ----
    f32x4 acc4 = {};
    #pragma unroll
    for (int k0 = 0; k0 < 128; k0 += 32) {
        bf16x8 af = *(const bf16x8*)&a1ls[(w * 16 + lm) * 136 + k0 + lq * 8];
        bf16x8 bf = *(const bf16x8*)&W2T[lm * 128 + k0 + lq * 8];
        acc4 = mfma16x16x32(af, bf, acc4);
    }
    if (lm < 10) {
        float bias = b2[lm];
        #pragma unroll
        for (int i = 0; i < 4; i++) {
            int r = rowbase + w * 16 + lq * 4 + i;
            out[(size_t)r * 10 + lm] = acc4[i] + bias;
        }
    }
}

extern "C" void kernel_launch(void* const* d_in, const int* in_sizes, int n_in,
                              void* d_out, int out_size, void* d_ws, size_t ws_size,
                              hipStream_t stream) {
    const float* x   = (const float*)d_in[0];
    const float* We1 = (const float*)d_in[1];
    const float* be1 = (const float*)d_in[2];
    const float* We2 = (const float*)d_in[3];
    const float* be2 = (const float*)d_in[4];
    const float* W1  = (const float*)d_in[5];
    const float* b1  = (const float*)d_in[6];
    const float* W2  = (const float*)d_in[7];
    const float* b2  = (const float*)d_in[8];
    float* out = (float*)d_out;

    char* ws = (char*)d_ws;
    uint16_t* We1T = (uint16_t*)(ws + WS_WE1T);
    uint16_t* We2T = (uint16_t*)(ws + WS_WE2T);
    uint16_t* W1T  = (uint16_t*)(ws + WS_W1T);
    uint16_t* W2T  = (uint16_t*)(ws + WS_W2T);

    hipLaunchKernelGGL(prep_weights, dim3(856), dim3(256), 0, stream,
                       We1, We2, W1, W2, We1T, We2T, W1T, W2T);
    hipLaunchKernelGGL(fused_kernel, dim3(1024), dim3(256), 0, stream,
                       x, We1T, be1, We2T, be2, W1T, b1, W2T, b2, out);
}